// Round 1
// baseline (644.071 us; speedup 1.0000x reference)
//
#include <hip/hip_runtime.h>
#include <math.h>

#define TT   512
#define BB   512
#define HID  32
#define EMB  32
#define FFD  16
#define NCLS 7

__device__ __forceinline__ float fast_rcp(float x) {
#if defined(__has_builtin)
#if __has_builtin(__builtin_amdgcn_rcpf)
    return __builtin_amdgcn_rcpf(x);
#else
    return 1.0f / x;
#endif
#else
    return 1.0f / x;
#endif
}

__device__ __forceinline__ float sigf(float x) {
    return fast_rcp(1.0f + __expf(-x));
}

// One wave (64 lanes) per batch element b. Lane j owns gate rows j and j+64.
// Fused: embedding gather + input proj + recurrent proj + gates + FF + logits.
// Writes UNNORMALIZED logits to out (T,B,7); softmax_t normalizes in-place after.
__global__ __launch_bounds__(64) void lstm_fused(
    const int* __restrict__ x, const float* __restrict__ emb,
    const float* __restrict__ W_ih, const float* __restrict__ W_hh,
    const float* __restrict__ b_ih, const float* __restrict__ b_hh,
    const float* __restrict__ W1, const float* __restrict__ b1,
    const float* __restrict__ W2, const float* __restrict__ b2,
    float* __restrict__ out)
{
    const int b    = blockIdx.x;
    const int lane = threadIdx.x;      // 0..63
    const int rA   = lane;             // gate row in [0,64)
    const int rB   = lane + 64;        // gate row in [64,128)
    const int m    = lane & 31;
    const bool lo  = lane < 32;

    __shared__ float sh_h[HID];
    __shared__ float sh_e[2][EMB];
    __shared__ float sh_z[FFD];
    __shared__ float sh_w1[FFD][HID + 1];   // +1 pad: conflict-free column reads
    __shared__ float sh_w2[NCLS][FFD + 1];

    // ---- one-time weight staging (registers) ----
    float wihA[HID], wihB[HID], whhA[HID], whhB[HID];
    #pragma unroll
    for (int k = 0; k < HID; k += 4) {
        float4 a;
        a = *(const float4*)(W_ih + rA*HID + k); wihA[k]=a.x; wihA[k+1]=a.y; wihA[k+2]=a.z; wihA[k+3]=a.w;
        a = *(const float4*)(W_ih + rB*HID + k); wihB[k]=a.x; wihB[k+1]=a.y; wihB[k+2]=a.z; wihB[k+3]=a.w;
        a = *(const float4*)(W_hh + rA*HID + k); whhA[k]=a.x; whhA[k+1]=a.y; whhA[k+2]=a.z; whhA[k+3]=a.w;
        a = *(const float4*)(W_hh + rB*HID + k); whhB[k]=a.x; whhB[k+1]=a.y; whhB[k+2]=a.z; whhB[k+3]=a.w;
    }
    const float biasA = b_ih[rA] + b_hh[rA];
    const float biasB = b_ih[rB] + b_hh[rB];
    const float b1v = (lane < FFD)  ? b1[lane] : 0.0f;
    const float b2v = (lane < NCLS) ? b2[lane] : 0.0f;

    for (int i = lane; i < FFD*HID;  i += 64) sh_w1[i >> 5][i & 31] = W1[i];
    for (int i = lane; i < NCLS*FFD; i += 64) sh_w2[i >> 4][i & 15] = W2[i];
    if (lo) sh_h[m] = 0.0f;

    // ---- x / embedding software pipeline (keep gather latency off the h-chain) ----
    int xv0 = x[b];            // x[t=0]
    int xv_n1 = x[BB + b];     // x[t=1]
    if (lo) sh_e[0][m] = emb[xv0*EMB + m];
    float c = 0.0f;
    __syncthreads();

    for (int t = 0; t < TT; ++t) {
        // prefetch e_{t+1} (uses xv_n1) and x_{t+2}
        float e_nxt = 0.0f;
        if ((t + 1 < TT) && lo) e_nxt = emb[xv_n1*EMB + m];
        int xv_n2 = (t + 2 < TT) ? x[(t + 2)*BB + b] : 0;

        const float* se = sh_e[t & 1];
        float accA = biasA, accB = biasB;
        #pragma unroll
        for (int k = 0; k < HID; ++k) {
            const float ek = se[k], hk = sh_h[k];
            accA = fmaf(wihA[k], ek, accA);
            accA = fmaf(whhA[k], hk, accA);
            accB = fmaf(wihB[k], ek, accB);
            accB = fmaf(whhB[k], hk, accB);
        }
        // lanes<32: rA -> i, rB -> g(tanh). lanes>=32: rA -> f, rB -> o.
        const float actA = sigf(accA);
        const float sB   = lo ? 2.0f*accB : accB;
        const float sgB  = sigf(sB);
        const float actB = lo ? (2.0f*sgB - 1.0f) : sgB;
        const float oA = __shfl_xor(actA, 32);
        const float oB = __shfl_xor(actB, 32);
        const float gi = lo ? actA : oA;
        const float gf = lo ? oA   : actA;
        const float gg = lo ? actB : oB;
        const float go = lo ? oB   : actB;
        c = gf*c + gi*gg;
        const float th = 2.0f*sigf(2.0f*c) - 1.0f;
        const float h  = go*th;

        if (lo) { sh_h[m] = h; sh_e[(t + 1) & 1][m] = e_nxt; }
        __syncthreads();

        // ---- FF head: z = relu(W1 h + b1) ----
        if (lane < FFD) {
            float z = b1v;
            #pragma unroll
            for (int k2 = 0; k2 < HID; ++k2) z = fmaf(sh_w1[lane][k2], sh_h[k2], z);
            sh_z[lane] = fmaxf(z, 0.0f);
        }
        __syncthreads();

        // ---- logits = W2 z + b2 -> d_out (unnormalized) ----
        if (lane < NCLS) {
            float l = b2v;
            #pragma unroll
            for (int f = 0; f < FFD; ++f) l = fmaf(sh_w2[lane][f], sh_z[f], l);
            out[(t*BB + b)*NCLS + lane] = l;
        }
        xv_n1 = xv_n2;
    }
}

// In-place softmax over the t axis. One wave per (b, class) column.
__global__ __launch_bounds__(64) void softmax_t(float* __restrict__ io)
{
    const int col  = blockIdx.x;          // b*NCLS + c
    const int lane = threadIdx.x;
    const int stride = BB * NCLS;         // 3584

    float v[TT / 64];
    float mx = -INFINITY;
    #pragma unroll
    for (int i = 0; i < TT/64; ++i) {
        v[i] = io[(lane + 64*i)*stride + col];
        mx = fmaxf(mx, v[i]);
    }
    #pragma unroll
    for (int off = 32; off; off >>= 1) mx = fmaxf(mx, __shfl_xor(mx, off));

    float s = 0.0f;
    #pragma unroll
    for (int i = 0; i < TT/64; ++i) { v[i] = __expf(v[i] - mx); s += v[i]; }
    #pragma unroll
    for (int off = 32; off; off >>= 1) s += __shfl_xor(s, off);

    const float inv = 1.0f / s;
    #pragma unroll
    for (int i = 0; i < TT/64; ++i) io[(lane + 64*i)*stride + col] = v[i]*inv;
}

extern "C" void kernel_launch(void* const* d_in, const int* in_sizes, int n_in,
                              void* d_out, int out_size, void* d_ws, size_t ws_size,
                              hipStream_t stream) {
    const int*   x   = (const int*)  d_in[0];
    const float* emb = (const float*)d_in[1];
    const float* Wih = (const float*)d_in[2];
    const float* Whh = (const float*)d_in[3];
    const float* bih = (const float*)d_in[4];
    const float* bhh = (const float*)d_in[5];
    const float* W1  = (const float*)d_in[6];
    const float* b1  = (const float*)d_in[7];
    const float* W2  = (const float*)d_in[8];
    const float* b2  = (const float*)d_in[9];
    float* out = (float*)d_out;

    lstm_fused<<<BB, 64, 0, stream>>>(x, emb, Wih, Whh, bih, bhh, W1, b1, W2, b2, out);
    softmax_t<<<BB*NCLS, 64, 0, stream>>>(out);
}

// Round 2
// 375.143 us; speedup vs baseline: 1.7169x; 1.7169x over previous
//
#include <hip/hip_runtime.h>
#include <math.h>

#define TT    512
#define BB    512
#define HID   32
#define EMB   32
#define FFD   16
#define NCLS  7
#define VOCABN 1000

__device__ __forceinline__ float rl(float v, int k) {
    return __int_as_float(__builtin_amdgcn_readlane(__float_as_int(v), k));
}
__device__ __forceinline__ float fast_rcp(float x) {
#if defined(__has_builtin)
#if __has_builtin(__builtin_amdgcn_rcpf)
    return __builtin_amdgcn_rcpf(x);
#else
    return 1.0f / x;
#endif
#else
    return 1.0f / x;
#endif
}
__device__ __forceinline__ float sigf(float x) { return fast_rcp(1.0f + __expf(-x)); }
__device__ __forceinline__ float tanh_fast(float x) { return 2.0f * sigf(2.0f * x) - 1.0f; }

// Precompute xg_table[v][r] = W_ih[r,:]·emb[v,:] + b_ih[r] + b_hh[r], stored
// interleaved as float2{row j, row j+64} so the main kernel's lane j does one
// coalesced dwordx2 load per step. 1000 blocks x 64 threads, trivial.
__global__ __launch_bounds__(64) void build_xg(
    const float* __restrict__ emb, const float* __restrict__ W_ih,
    const float* __restrict__ b_ih, const float* __restrict__ b_hh,
    float2* __restrict__ tab)
{
    const int v = blockIdx.x;
    const int j = threadIdx.x;
    const float* e  = emb + v * EMB;            // uniform address -> s_load
    const float* w0 = W_ih + j * EMB;
    const float* w1 = W_ih + (j + 64) * EMB;
    float a0 = b_ih[j]      + b_hh[j];
    float a1 = b_ih[j + 64] + b_hh[j + 64];
    #pragma unroll
    for (int k = 0; k < EMB; ++k) {
        const float ek = e[k];
        a0 = fmaf(w0[k], ek, a0);
        a1 = fmaf(w1[k], ek, a1);
    }
    tab[v * 64 + j] = make_float2(a0, a1);
}

// One wave per batch chain. No LDS, no barriers: h broadcast via v_readlane,
// gate rows j (i/f) and j+64 (g/o) per lane, cross-half shfl_xor(32) combines.
// FF head for step t-1 is computed at the top of step t (reuses the hs[]
// broadcast, independent of step-t recurrence -> fills latency slots).
// Softmax over t is fused: online (m,s) per class + in-place normalize pass.
template <bool TAB>
__global__ __launch_bounds__(64) void lstm_all(
    const int* __restrict__ x, const float* __restrict__ emb,
    const float* __restrict__ W_ih, const float* __restrict__ W_hh,
    const float* __restrict__ b_ih, const float* __restrict__ b_hh,
    const float* __restrict__ W1, const float* __restrict__ b1,
    const float* __restrict__ W2, const float* __restrict__ b2,
    const float2* __restrict__ tab, float* __restrict__ out)
{
    const int b  = blockIdx.x;
    const int j  = threadIdx.x;        // 0..63
    const int m  = j & 31;
    const bool lo = j < 32;
    const int rA = j, rB = j + 64;

    // ---- weights to registers ----
    float whhA[HID], whhB[HID];
    #pragma unroll
    for (int k = 0; k < HID; k += 4) {
        float4 a;
        a = *(const float4*)(W_hh + rA * HID + k); whhA[k]=a.x; whhA[k+1]=a.y; whhA[k+2]=a.z; whhA[k+3]=a.w;
        a = *(const float4*)(W_hh + rB * HID + k); whhB[k]=a.x; whhB[k+1]=a.y; whhB[k+2]=a.z; whhB[k+3]=a.w;
    }
    float wihA[HID], wihB[HID];
    float biasA = 0.f, biasB = 0.f;
    if constexpr (!TAB) {
        #pragma unroll
        for (int k = 0; k < HID; k += 4) {
            float4 a;
            a = *(const float4*)(W_ih + rA * HID + k); wihA[k]=a.x; wihA[k+1]=a.y; wihA[k+2]=a.z; wihA[k+3]=a.w;
            a = *(const float4*)(W_ih + rB * HID + k); wihB[k]=a.x; wihB[k+1]=a.y; wihB[k+2]=a.z; wihB[k+3]=a.w;
        }
        biasA = b_ih[rA] + b_hh[rA];
        biasB = b_ih[rB] + b_hh[rB];
    }
    const int f16 = j & 15;
    float w1r[HID];
    #pragma unroll
    for (int k = 0; k < HID; ++k) w1r[k] = W1[f16 * HID + k];
    const int cls = j & 7;
    const int c7  = (cls < NCLS) ? cls : 0;
    float w2r[FFD];
    #pragma unroll
    for (int f = 0; f < FFD; ++f) w2r[f] = W2[c7 * FFD + f];
    const float b1v = b1[f16];
    const float b2v = b2[c7];

    float h = 0.f, c = 0.f;
    float mrun = -3.0e38f, srun = 0.f;   // online softmax state, class = j&7

    auto gates = [&](float accA, float accB) {
        // lanes<32: accA->i (sig), accB->g (tanh); lanes>=32: accA->f, accB->o (sig)
        const float actA = sigf(accA);
        const float sB   = lo ? 2.0f * accB : accB;
        const float sgB  = sigf(sB);
        const float actB = lo ? 2.0f * sgB - 1.0f : sgB;
        const float oA = __shfl_xor(actA, 32);
        const float oB = __shfl_xor(actB, 32);
        const float gi = lo ? actA : oA;
        const float gf = lo ? oA   : actA;
        const float gg = lo ? actB : oB;
        const float go = lo ? oB   : actB;
        c = fmaf(gf, c, gi * gg);
        h = go * tanh_fast(c);
    };

    auto ff_head = [&](int t_out, const float* hs) {
        float z0 = b1v, z1 = 0.f;
        #pragma unroll
        for (int k = 0; k < HID; k += 2) {
            z0 = fmaf(w1r[k],     hs[k],     z0);
            z1 = fmaf(w1r[k + 1], hs[k + 1], z1);
        }
        const float z = fmaxf(z0 + z1, 0.0f);   // lane j holds z[j&15]
        float lg = b2v;
        #pragma unroll
        for (int f = 0; f < FFD; ++f) lg = fmaf(w2r[f], rl(z, f), lg);
        const float mn = fmaxf(mrun, lg);
        srun = fmaf(srun, __expf(mrun - mn), __expf(lg - mn));
        mrun = mn;
        if (j < NCLS) out[(t_out * BB + b) * NCLS + j] = lg;
    };

    // ---- input pipeline: xg (or e) prefetched one step ahead ----
    int xvn1 = x[1 * BB + b];
    int xvn2 = x[2 * BB + b];
    float2 xg = make_float2(0.f, 0.f);
    float eA = 0.f;
    if constexpr (TAB) xg = tab[(size_t)x[b] * 64 + j];
    else               eA = emb[x[b] * EMB + m];

    // ---- t = 0 (h = 0: recurrent dot vanishes) ----
    if constexpr (TAB) {
        gates(xg.x, xg.y);
    } else {
        float es[EMB];
        #pragma unroll
        for (int k = 0; k < EMB; ++k) es[k] = rl(eA, k);
        float p0 = biasA, p1 = 0.f, q0 = biasB, q1 = 0.f;
        #pragma unroll
        for (int k = 0; k < EMB; k += 2) {
            p0 = fmaf(wihA[k],   es[k],   p0); p1 = fmaf(wihA[k+1], es[k+1], p1);
            q0 = fmaf(wihB[k],   es[k],   q0); q1 = fmaf(wihB[k+1], es[k+1], q1);
        }
        gates(p0 + p1, q0 + q1);
    }
    if constexpr (TAB) xg = tab[(size_t)xvn1 * 64 + j];
    else               eA = emb[xvn1 * EMB + m];
    xvn1 = xvn2;
    xvn2 = x[3 * BB + b];

    // ---- main loop t = 1 .. TT-1 ----
    for (int t = 1; t < TT; ++t) {
        // prefetch inputs for step t+1 (off the h-chain)
        float2 xg_n = make_float2(0.f, 0.f);
        float  e_n  = 0.f;
        if (t + 1 < TT) {
            if constexpr (TAB) xg_n = tab[(size_t)xvn1 * 64 + j];
            else               e_n  = emb[xvn1 * EMB + m];
        }
        const int xv_n3 = (t + 3 < TT) ? x[(t + 3) * BB + b] : 0;

        // broadcast h (state after step t-1): SGPRs via readlane
        float hs[HID];
        #pragma unroll
        for (int k = 0; k < HID; ++k) hs[k] = rl(h, k);

        // FF + logits + online softmax for step t-1 (independent work)
        ff_head(t - 1, hs);

        // recurrent dot for step t: 4 chains of 16
        float p0, p1 = 0.f, q0, q1 = 0.f;
        if constexpr (TAB) { p0 = xg.x; q0 = xg.y; }
        else               { p0 = biasA; q0 = biasB; }
        if constexpr (!TAB) {
            float es[EMB];
            #pragma unroll
            for (int k = 0; k < EMB; ++k) es[k] = rl(eA, k);
            #pragma unroll
            for (int k = 0; k < EMB; k += 2) {
                p0 = fmaf(wihA[k],   es[k],   p0); p1 = fmaf(wihA[k+1], es[k+1], p1);
                q0 = fmaf(wihB[k],   es[k],   q0); q1 = fmaf(wihB[k+1], es[k+1], q1);
            }
        }
        #pragma unroll
        for (int k = 0; k < HID; k += 2) {
            p0 = fmaf(whhA[k],   hs[k],   p0); p1 = fmaf(whhA[k+1], hs[k+1], p1);
            q0 = fmaf(whhB[k],   hs[k],   q0); q1 = fmaf(whhB[k+1], hs[k+1], q1);
        }
        gates(p0 + p1, q0 + q1);

        xg = xg_n; eA = e_n; xvn1 = xvn2; xvn2 = xv_n3;
    }

    // ---- epilogue: FF for the last step ----
    {
        float hs[HID];
        #pragma unroll
        for (int k = 0; k < HID; ++k) hs[k] = rl(h, k);
        ff_head(TT - 1, hs);
    }

    // ---- in-place softmax normalize over t (this wave wrote all its logits) ----
    #pragma unroll 1
    for (int cc = 0; cc < NCLS; ++cc) {
        const float mc = rl(mrun, cc);       // class cc lives in lane cc
        const float sc = rl(srun, cc);
        const float ic = 1.0f / sc;
        #pragma unroll
        for (int i = 0; i < TT / 64; ++i) {
            const int t = j + 64 * i;
            const int a = (t * BB + b) * NCLS + cc;
            out[a] = __expf(out[a] - mc) * ic;
        }
    }
}

extern "C" void kernel_launch(void* const* d_in, const int* in_sizes, int n_in,
                              void* d_out, int out_size, void* d_ws, size_t ws_size,
                              hipStream_t stream) {
    const int*   x   = (const int*)  d_in[0];
    const float* emb = (const float*)d_in[1];
    const float* Wih = (const float*)d_in[2];
    const float* Whh = (const float*)d_in[3];
    const float* bih = (const float*)d_in[4];
    const float* bhh = (const float*)d_in[5];
    const float* W1  = (const float*)d_in[6];
    const float* b1  = (const float*)d_in[7];
    const float* W2  = (const float*)d_in[8];
    const float* b2  = (const float*)d_in[9];
    float* out = (float*)d_out;

    const size_t tab_bytes = (size_t)VOCABN * 128 * sizeof(float);
    if (ws_size >= tab_bytes) {
        float2* tab = (float2*)d_ws;
        build_xg<<<VOCABN, 64, 0, stream>>>(emb, Wih, bih, bhh, tab);
        lstm_all<true><<<BB, 64, 0, stream>>>(x, emb, Wih, Whh, bih, bhh,
                                              W1, b1, W2, b2, tab, out);
    } else {
        lstm_all<false><<<BB, 64, 0, stream>>>(x, emb, Wih, Whh, bih, bhh,
                                               W1, b1, W2, b2, nullptr, out);
    }
}

// Round 3
// 331.081 us; speedup vs baseline: 1.9454x; 1.1331x over previous
//
#include <hip/hip_runtime.h>
#include <math.h>

#define TT    512
#define BB    512
#define HID   32
#define EMB   32
#define FFD   16
#define NCLS  7
#define VOCABN 1000

__device__ __forceinline__ float rl(float v, int k) {
    return __int_as_float(__builtin_amdgcn_readlane(__float_as_int(v), k));
}
__device__ __forceinline__ float fast_rcp(float x) {
#if defined(__has_builtin)
#if __has_builtin(__builtin_amdgcn_rcpf)
    return __builtin_amdgcn_rcpf(x);
#else
    return 1.0f / x;
#endif
#else
    return 1.0f / x;
#endif
}
__device__ __forceinline__ float sigf(float x) { return fast_rcp(1.0f + __expf(-x)); }
__device__ __forceinline__ float tanh_fast(float x) { return 2.0f * sigf(2.0f * x) - 1.0f; }

// xg_table[v][j] = {W_ih[j,:]·emb[v,:]+b[j], W_ih[j+64,:]·emb[v,:]+b[j+64]}
__global__ __launch_bounds__(64) void build_xg(
    const float* __restrict__ emb, const float* __restrict__ W_ih,
    const float* __restrict__ b_ih, const float* __restrict__ b_hh,
    float2* __restrict__ tab)
{
    const int v = blockIdx.x;
    const int j = threadIdx.x;
    const float* e  = emb + v * EMB;
    const float* w0 = W_ih + j * EMB;
    const float* w1 = W_ih + (j + 64) * EMB;
    float a0 = b_ih[j]      + b_hh[j];
    float a1 = b_ih[j + 64] + b_hh[j + 64];
    #pragma unroll
    for (int k = 0; k < EMB; ++k) {
        const float ek = e[k];
        a0 = fmaf(w0[k], ek, a0);
        a1 = fmaf(w1[k], ek, a1);
    }
    tab[v * 64 + j] = make_float2(a0, a1);
}

// Serial recurrence ONLY. One wave per chain, h broadcast via v_readlane,
// xg table prefetched 2 steps ahead, h stored to hs[b][t][32] each step.
__global__ __launch_bounds__(64) void lstm_rec(
    const int* __restrict__ x, const float2* __restrict__ tab,
    const float* __restrict__ W_hh, float* __restrict__ hsout)
{
    const int b  = blockIdx.x;
    const int j  = threadIdx.x;
    const int m  = j & 31;
    const bool lo = j < 32;

    float whhA[HID], whhB[HID];
    #pragma unroll
    for (int k = 0; k < HID; k += 4) {
        float4 a;
        a = *(const float4*)(W_hh + j * HID + k);        whhA[k]=a.x; whhA[k+1]=a.y; whhA[k+2]=a.z; whhA[k+3]=a.w;
        a = *(const float4*)(W_hh + (j + 64) * HID + k); whhB[k]=a.x; whhB[k+1]=a.y; whhB[k+2]=a.z; whhB[k+3]=a.w;
    }

    float h = 0.f, c = 0.f;
    auto gates = [&](float accA, float accB) {
        const float actA = sigf(accA);
        const float sB   = lo ? 2.0f * accB : accB;
        const float sgB  = sigf(sB);
        const float actB = lo ? 2.0f * sgB - 1.0f : sgB;
        const float oA = __shfl_xor(actA, 32);
        const float oB = __shfl_xor(actB, 32);
        const float gi = lo ? actA : oA;
        const float gf = lo ? oA   : actA;
        const float gg = lo ? actB : oB;
        const float go = lo ? oB   : actB;
        c = fmaf(gf, c, gi * gg);
        h = go * tanh_fast(c);
    };

    float* hrow = hsout + (size_t)b * TT * HID + m;

    // ---- pipeline: tab prefetched 2 deep, x 4 deep ----
    int xc = x[3 * BB + b], xd = x[4 * BB + b];
    float2 g0  = tab[(size_t)x[b] * 64 + j];
    float2 xg  = tab[(size_t)x[1 * BB + b] * 64 + j];   // t=1
    float2 xg1 = tab[(size_t)x[2 * BB + b] * 64 + j];   // t=2

    gates(g0.x, g0.y);                                   // t=0 (h=0)
    if (lo) hrow[0] = h;

    for (int t = 1; t < TT; ++t) {
        float2 xg2 = make_float2(0.f, 0.f);
        if (t + 2 < TT) xg2 = tab[(size_t)xc * 64 + j];
        const int xnew = (t + 4 < TT) ? x[(t + 4) * BB + b] : 0;

        float hs[HID];
        #pragma unroll
        for (int k = 0; k < HID; ++k) hs[k] = rl(h, k);

        float p0 = xg.x, p1 = 0.f, q0 = xg.y, q1 = 0.f;
        #pragma unroll
        for (int k = 0; k < HID; k += 2) {
            p0 = fmaf(whhA[k],   hs[k],   p0); p1 = fmaf(whhA[k+1], hs[k+1], p1);
            q0 = fmaf(whhB[k],   hs[k],   q0); q1 = fmaf(whhB[k+1], hs[k+1], q1);
        }
        gates(p0 + p1, q0 + q1);
        if (lo) hrow[t * HID] = h;

        xg = xg1; xg1 = xg2; xc = xd; xd = xnew;
    }
}

// FF + logits + softmax-over-t, one block per b, 2 timesteps per thread.
// W1/b1/W2/b2 accesses are wave-uniform -> scalar loads.
__global__ __launch_bounds__(256) void ff_softmax(
    const float* __restrict__ hs,
    const float* __restrict__ W1, const float* __restrict__ b1,
    const float* __restrict__ W2, const float* __restrict__ b2,
    float* __restrict__ out)
{
    const int b    = blockIdx.x;
    const int tid  = threadIdx.x;
    const int lane = tid & 63, wv = tid >> 6;
    const int t0   = tid * 2;

    __shared__ float redM[4][NCLS];
    __shared__ float redS[4][NCLS];

    float4 hv[16];
    const float4* hb = (const float4*)(hs + ((size_t)b * TT + t0) * HID);
    #pragma unroll
    for (int q = 0; q < 16; ++q) hv[q] = hb[q];

    float lg[2][NCLS];
    #pragma unroll
    for (int r = 0; r < 2; ++r) {
        const float* hr = (const float*)(hv + 8 * r);
        float z[FFD];
        #pragma unroll
        for (int f = 0; f < FFD; ++f) {
            float a = b1[f];
            #pragma unroll
            for (int k = 0; k < HID; ++k) a = fmaf(W1[f * HID + k], hr[k], a);
            z[f] = fmaxf(a, 0.f);
        }
        #pragma unroll
        for (int cc = 0; cc < NCLS; ++cc) {
            float a = b2[cc];
            #pragma unroll
            for (int f = 0; f < FFD; ++f) a = fmaf(W2[cc * FFD + f], z[f], a);
            lg[r][cc] = a;
        }
    }

    float M[NCLS], S[NCLS];
    #pragma unroll
    for (int cc = 0; cc < NCLS; ++cc) {
        float mm = fmaxf(lg[0][cc], lg[1][cc]);
        #pragma unroll
        for (int off = 32; off; off >>= 1) mm = fmaxf(mm, __shfl_xor(mm, off));
        if (lane == 0) redM[wv][cc] = mm;
    }
    __syncthreads();
    #pragma unroll
    for (int cc = 0; cc < NCLS; ++cc)
        M[cc] = fmaxf(fmaxf(redM[0][cc], redM[1][cc]), fmaxf(redM[2][cc], redM[3][cc]));

    #pragma unroll
    for (int cc = 0; cc < NCLS; ++cc) {
        float ss = __expf(lg[0][cc] - M[cc]) + __expf(lg[1][cc] - M[cc]);
        #pragma unroll
        for (int off = 32; off; off >>= 1) ss += __shfl_xor(ss, off);
        if (lane == 0) redS[wv][cc] = ss;
    }
    __syncthreads();
    #pragma unroll
    for (int cc = 0; cc < NCLS; ++cc)
        S[cc] = (redS[0][cc] + redS[1][cc]) + (redS[2][cc] + redS[3][cc]);

    #pragma unroll
    for (int r = 0; r < 2; ++r) {
        float* o = out + ((size_t)(t0 + r) * BB + b) * NCLS;
        #pragma unroll
        for (int cc = 0; cc < NCLS; ++cc)
            o[cc] = __expf(lg[r][cc] - M[cc]) * fast_rcp(S[cc]);
    }
}

// ---------------- round-2 verified fused kernel (fallback paths) ----------------
template <bool TAB>
__global__ __launch_bounds__(64) void lstm_all(
    const int* __restrict__ x, const float* __restrict__ emb,
    const float* __restrict__ W_ih, const float* __restrict__ W_hh,
    const float* __restrict__ b_ih, const float* __restrict__ b_hh,
    const float* __restrict__ W1, const float* __restrict__ b1,
    const float* __restrict__ W2, const float* __restrict__ b2,
    const float2* __restrict__ tab, float* __restrict__ out)
{
    const int b  = blockIdx.x;
    const int j  = threadIdx.x;
    const int m  = j & 31;
    const bool lo = j < 32;
    const int rA = j, rB = j + 64;

    float whhA[HID], whhB[HID];
    #pragma unroll
    for (int k = 0; k < HID; k += 4) {
        float4 a;
        a = *(const float4*)(W_hh + rA * HID + k); whhA[k]=a.x; whhA[k+1]=a.y; whhA[k+2]=a.z; whhA[k+3]=a.w;
        a = *(const float4*)(W_hh + rB * HID + k); whhB[k]=a.x; whhB[k+1]=a.y; whhB[k+2]=a.z; whhB[k+3]=a.w;
    }
    float wihA[HID], wihB[HID];
    float biasA = 0.f, biasB = 0.f;
    if constexpr (!TAB) {
        #pragma unroll
        for (int k = 0; k < HID; k += 4) {
            float4 a;
            a = *(const float4*)(W_ih + rA * HID + k); wihA[k]=a.x; wihA[k+1]=a.y; wihA[k+2]=a.z; wihA[k+3]=a.w;
            a = *(const float4*)(W_ih + rB * HID + k); wihB[k]=a.x; wihB[k+1]=a.y; wihB[k+2]=a.z; wihB[k+3]=a.w;
        }
        biasA = b_ih[rA] + b_hh[rA];
        biasB = b_ih[rB] + b_hh[rB];
    }
    const int f16 = j & 15;
    float w1r[HID];
    #pragma unroll
    for (int k = 0; k < HID; ++k) w1r[k] = W1[f16 * HID + k];
    const int cls = j & 7;
    const int c7  = (cls < NCLS) ? cls : 0;
    float w2r[FFD];
    #pragma unroll
    for (int f = 0; f < FFD; ++f) w2r[f] = W2[c7 * FFD + f];
    const float b1v = b1[f16];
    const float b2v = b2[c7];

    float h = 0.f, c = 0.f;
    float mrun = -3.0e38f, srun = 0.f;

    auto gates = [&](float accA, float accB) {
        const float actA = sigf(accA);
        const float sB   = lo ? 2.0f * accB : accB;
        const float sgB  = sigf(sB);
        const float actB = lo ? 2.0f * sgB - 1.0f : sgB;
        const float oA = __shfl_xor(actA, 32);
        const float oB = __shfl_xor(actB, 32);
        const float gi = lo ? actA : oA;
        const float gf = lo ? oA   : actA;
        const float gg = lo ? actB : oB;
        const float go = lo ? oB   : actB;
        c = fmaf(gf, c, gi * gg);
        h = go * tanh_fast(c);
    };

    auto ff_head = [&](int t_out, const float* hsv) {
        float z0 = b1v, z1 = 0.f;
        #pragma unroll
        for (int k = 0; k < HID; k += 2) {
            z0 = fmaf(w1r[k],     hsv[k],     z0);
            z1 = fmaf(w1r[k + 1], hsv[k + 1], z1);
        }
        const float z = fmaxf(z0 + z1, 0.0f);
        float lgv = b2v;
        #pragma unroll
        for (int f = 0; f < FFD; ++f) lgv = fmaf(w2r[f], rl(z, f), lgv);
        const float mn = fmaxf(mrun, lgv);
        srun = fmaf(srun, __expf(mrun - mn), __expf(lgv - mn));
        mrun = mn;
        if (j < NCLS) out[(t_out * BB + b) * NCLS + j] = lgv;
    };

    int xvn1 = x[1 * BB + b];
    int xvn2 = x[2 * BB + b];
    float2 xg = make_float2(0.f, 0.f);
    float eA = 0.f;
    if constexpr (TAB) xg = tab[(size_t)x[b] * 64 + j];
    else               eA = emb[x[b] * EMB + m];

    if constexpr (TAB) {
        gates(xg.x, xg.y);
    } else {
        float es[EMB];
        #pragma unroll
        for (int k = 0; k < EMB; ++k) es[k] = rl(eA, k);
        float p0 = biasA, p1 = 0.f, q0 = biasB, q1 = 0.f;
        #pragma unroll
        for (int k = 0; k < EMB; k += 2) {
            p0 = fmaf(wihA[k],   es[k],   p0); p1 = fmaf(wihA[k+1], es[k+1], p1);
            q0 = fmaf(wihB[k],   es[k],   q0); q1 = fmaf(wihB[k+1], es[k+1], q1);
        }
        gates(p0 + p1, q0 + q1);
    }
    if constexpr (TAB) xg = tab[(size_t)xvn1 * 64 + j];
    else               eA = emb[xvn1 * EMB + m];
    xvn1 = xvn2;
    xvn2 = x[3 * BB + b];

    for (int t = 1; t < TT; ++t) {
        float2 xg_n = make_float2(0.f, 0.f);
        float  e_n  = 0.f;
        if (t + 1 < TT) {
            if constexpr (TAB) xg_n = tab[(size_t)xvn1 * 64 + j];
            else               e_n  = emb[xvn1 * EMB + m];
        }
        const int xv_n3 = (t + 3 < TT) ? x[(t + 3) * BB + b] : 0;

        float hsv[HID];
        #pragma unroll
        for (int k = 0; k < HID; ++k) hsv[k] = rl(h, k);

        ff_head(t - 1, hsv);

        float p0, p1 = 0.f, q0, q1 = 0.f;
        if constexpr (TAB) { p0 = xg.x; q0 = xg.y; }
        else               { p0 = biasA; q0 = biasB; }
        if constexpr (!TAB) {
            float es[EMB];
            #pragma unroll
            for (int k = 0; k < EMB; ++k) es[k] = rl(eA, k);
            #pragma unroll
            for (int k = 0; k < EMB; k += 2) {
                p0 = fmaf(wihA[k],   es[k],   p0); p1 = fmaf(wihA[k+1], es[k+1], p1);
                q0 = fmaf(wihB[k],   es[k],   q0); q1 = fmaf(wihB[k+1], es[k+1], q1);
            }
        }
        #pragma unroll
        for (int k = 0; k < HID; k += 2) {
            p0 = fmaf(whhA[k],   hsv[k],   p0); p1 = fmaf(whhA[k+1], hsv[k+1], p1);
            q0 = fmaf(whhB[k],   hsv[k],   q0); q1 = fmaf(whhB[k+1], hsv[k+1], q1);
        }
        gates(p0 + p1, q0 + q1);

        xg = xg_n; eA = e_n; xvn1 = xvn2; xvn2 = xv_n3;
    }

    {
        float hsv[HID];
        #pragma unroll
        for (int k = 0; k < HID; ++k) hsv[k] = rl(h, k);
        ff_head(TT - 1, hsv);
    }

    #pragma unroll 1
    for (int cc = 0; cc < NCLS; ++cc) {
        const float mc = rl(mrun, cc);
        const float sc = rl(srun, cc);
        const float ic = 1.0f / sc;
        #pragma unroll
        for (int i = 0; i < TT / 64; ++i) {
            const int t = j + 64 * i;
            const int a = (t * BB + b) * NCLS + cc;
            out[a] = __expf(out[a] - mc) * ic;
        }
    }
}

extern "C" void kernel_launch(void* const* d_in, const int* in_sizes, int n_in,
                              void* d_out, int out_size, void* d_ws, size_t ws_size,
                              hipStream_t stream) {
    const int*   x   = (const int*)  d_in[0];
    const float* emb = (const float*)d_in[1];
    const float* Wih = (const float*)d_in[2];
    const float* Whh = (const float*)d_in[3];
    const float* bih = (const float*)d_in[4];
    const float* bhh = (const float*)d_in[5];
    const float* W1  = (const float*)d_in[6];
    const float* b1  = (const float*)d_in[7];
    const float* W2  = (const float*)d_in[8];
    const float* b2  = (const float*)d_in[9];
    float* out = (float*)d_out;

    const size_t tab_bytes = (size_t)VOCABN * 128 * sizeof(float);   // 512 000
    const size_t hs_off    = 524288;                                 // 512 KiB align
    const size_t hs_bytes  = (size_t)BB * TT * HID * sizeof(float);  // 32 MiB
    if (ws_size >= hs_off + hs_bytes) {
        float2* tab = (float2*)d_ws;
        float*  hs  = (float*)((char*)d_ws + hs_off);
        build_xg<<<VOCABN, 64, 0, stream>>>(emb, Wih, bih, bhh, tab);
        lstm_rec<<<BB, 64, 0, stream>>>(x, tab, Whh, hs);
        ff_softmax<<<BB, 256, 0, stream>>>(hs, W1, b1, W2, b2, out);
    } else if (ws_size >= tab_bytes) {
        float2* tab = (float2*)d_ws;
        build_xg<<<VOCABN, 64, 0, stream>>>(emb, Wih, bih, bhh, tab);
        lstm_all<true><<<BB, 64, 0, stream>>>(x, emb, Wih, Whh, bih, bhh,
                                              W1, b1, W2, b2, tab, out);
    } else {
        lstm_all<false><<<BB, 64, 0, stream>>>(x, emb, Wih, Whh, bih, bhh,
                                               W1, b1, W2, b2, nullptr, out);
    }
}

// Round 4
// 293.404 us; speedup vs baseline: 2.1952x; 1.1284x over previous
//
#include <hip/hip_runtime.h>
#include <math.h>

#define TT    512
#define BB    512
#define HID   32
#define EMB   32
#define FFD   16
#define NCLS  7
#define VOCABN 1000

__device__ __forceinline__ float rl(float v, int k) {
    return __int_as_float(__builtin_amdgcn_readlane(__float_as_int(v), k));
}
__device__ __forceinline__ float fast_rcp(float x) {
#if defined(__has_builtin)
#if __has_builtin(__builtin_amdgcn_rcpf)
    return __builtin_amdgcn_rcpf(x);
#else
    return 1.0f / x;
#endif
#else
    return 1.0f / x;
#endif
}
__device__ __forceinline__ float sigf(float x) { return fast_rcp(1.0f + __expf(-x)); }
__device__ __forceinline__ float tanh_fast(float x) { return 2.0f * sigf(2.0f * x) - 1.0f; }

// xg_table[v][j] = {W_ih[j,:]·emb[v,:]+b[j], W_ih[j+64,:]·emb[v,:]+b[j+64]}
__global__ __launch_bounds__(64) void build_xg(
    const float* __restrict__ emb, const float* __restrict__ W_ih,
    const float* __restrict__ b_ih, const float* __restrict__ b_hh,
    float2* __restrict__ tab)
{
    const int v = blockIdx.x;
    const int j = threadIdx.x;
    const float* e  = emb + v * EMB;
    const float* w0 = W_ih + j * EMB;
    const float* w1 = W_ih + (j + 64) * EMB;
    float a0 = b_ih[j]      + b_hh[j];
    float a1 = b_ih[j + 64] + b_hh[j + 64];
    #pragma unroll
    for (int k = 0; k < EMB; ++k) {
        const float ek = e[k];
        a0 = fmaf(w0[k], ek, a0);
        a1 = fmaf(w1[k], ek, a1);
    }
    tab[v * 64 + j] = make_float2(a0, a1);
}

// Serial recurrence ONLY. One wave per chain.
// __launch_bounds__(64,1): occupancy is grid-limited (512 waves on 1024 SIMDs)
// so give the register allocator the FULL budget -> W_hh stays resident
// (round-3 VGPR_Count=44 proved the weights were being spilled/reloaded
// inside the serial loop).
// h staged in LDS per step (ds_write, no vmcnt), flushed to global every 8
// steps as one dwordx4 per lane -> 8x fewer stores polluting vmcnt waits.
__global__ __launch_bounds__(64, 1) void lstm_rec(
    const int* __restrict__ x, const float2* __restrict__ tab,
    const float* __restrict__ W_hh, float* __restrict__ hsout)
{
    const int b  = blockIdx.x;
    const int j  = threadIdx.x;
    const int m  = j & 31;
    const bool lo = j < 32;

    __shared__ float sh[8 * HID];

    float whhA[HID], whhB[HID];
    #pragma unroll
    for (int k = 0; k < HID; k += 4) {
        float4 a;
        a = *(const float4*)(W_hh + j * HID + k);        whhA[k]=a.x; whhA[k+1]=a.y; whhA[k+2]=a.z; whhA[k+3]=a.w;
        a = *(const float4*)(W_hh + (j + 64) * HID + k); whhB[k]=a.x; whhB[k+1]=a.y; whhB[k+2]=a.z; whhB[k+3]=a.w;
    }

    float h = 0.f, c = 0.f;
    float* hrow0 = hsout + (size_t)b * TT * HID;

    // ---- pipeline: tab 2 deep, x 4 deep (x addresses are wave-uniform -> s_load) ----
    int xc = x[2 * BB + b], xd = x[3 * BB + b];
    float2 xg  = tab[(size_t)x[b] * 64 + j];            // t=0
    float2 xg1 = tab[(size_t)x[1 * BB + b] * 64 + j];   // t=1

    for (int t8 = 0; t8 < TT / 8; ++t8) {
        #pragma unroll
        for (int u = 0; u < 8; ++u) {
            const int t = t8 * 8 + u;
            // prefetch xg for t+2, x for t+4 (clamped; tail values unused)
            float2 xg2 = tab[(size_t)xc * 64 + j];
            const int tn = (t + 4 < TT) ? (t + 4) : (TT - 1);
            const int xnew = x[tn * BB + b];

            // broadcast h (t=0: h=0, dot contributes nothing -> uniform loop)
            float hs[HID];
            #pragma unroll
            for (int k = 0; k < HID; ++k) hs[k] = rl(h, k);

            float p0 = xg.x, p1 = 0.f, q0 = xg.y, q1 = 0.f;
            #pragma unroll
            for (int k = 0; k < HID; k += 2) {
                p0 = fmaf(whhA[k],   hs[k],   p0); p1 = fmaf(whhA[k+1], hs[k+1], p1);
                q0 = fmaf(whhB[k],   hs[k],   q0); q1 = fmaf(whhB[k+1], hs[k+1], q1);
            }
            const float accA = p0 + p1, accB = q0 + q1;

            // lanes<32: accA->i (sig), accB->g (tanh); lanes>=32: accA->f, accB->o
            const float actA = sigf(accA);
            const float sB   = lo ? 2.0f * accB : accB;
            const float sgB  = sigf(sB);
            const float actB = lo ? 2.0f * sgB - 1.0f : sgB;
            const float oA = __shfl_xor(actA, 32);
            const float oB = __shfl_xor(actB, 32);
            const float gi = lo ? actA : oA;
            const float gf = lo ? oA   : actA;
            const float gg = lo ? actB : oB;
            const float go = lo ? oB   : actB;
            c = fmaf(gf, c, gi * gg);
            h = go * tanh_fast(c);

            if (lo) sh[u * HID + m] = h;     // LDS stage (no vmcnt)
            xg = xg1; xg1 = xg2; xc = xd; xd = xnew;
        }
        // flush 8 steps: 256 floats, one float4 per lane, coalesced 1KB store
        const float4 v = *(const float4*)(sh + j * 4);
        *(float4*)(hrow0 + t8 * 8 * HID + j * 4) = v;
    }
}

// FF + logits + softmax-over-t, one block per b, 2 timesteps per thread.
__global__ __launch_bounds__(256) void ff_softmax(
    const float* __restrict__ hs,
    const float* __restrict__ W1, const float* __restrict__ b1,
    const float* __restrict__ W2, const float* __restrict__ b2,
    float* __restrict__ out)
{
    const int b    = blockIdx.x;
    const int tid  = threadIdx.x;
    const int lane = tid & 63, wv = tid >> 6;
    const int t0   = tid * 2;

    __shared__ float redM[4][NCLS];
    __shared__ float redS[4][NCLS];

    float4 hv[16];
    const float4* hb = (const float4*)(hs + ((size_t)b * TT + t0) * HID);
    #pragma unroll
    for (int q = 0; q < 16; ++q) hv[q] = hb[q];

    float lg[2][NCLS];
    #pragma unroll
    for (int r = 0; r < 2; ++r) {
        const float* hr = (const float*)(hv + 8 * r);
        float z[FFD];
        #pragma unroll
        for (int f = 0; f < FFD; ++f) {
            float a = b1[f];
            #pragma unroll
            for (int k = 0; k < HID; ++k) a = fmaf(W1[f * HID + k], hr[k], a);
            z[f] = fmaxf(a, 0.f);
        }
        #pragma unroll
        for (int cc = 0; cc < NCLS; ++cc) {
            float a = b2[cc];
            #pragma unroll
            for (int f = 0; f < FFD; ++f) a = fmaf(W2[cc * FFD + f], z[f], a);
            lg[r][cc] = a;
        }
    }

    float M[NCLS], S[NCLS];
    #pragma unroll
    for (int cc = 0; cc < NCLS; ++cc) {
        float mm = fmaxf(lg[0][cc], lg[1][cc]);
        #pragma unroll
        for (int off = 32; off; off >>= 1) mm = fmaxf(mm, __shfl_xor(mm, off));
        if (lane == 0) redM[wv][cc] = mm;
    }
    __syncthreads();
    #pragma unroll
    for (int cc = 0; cc < NCLS; ++cc)
        M[cc] = fmaxf(fmaxf(redM[0][cc], redM[1][cc]), fmaxf(redM[2][cc], redM[3][cc]));

    #pragma unroll
    for (int cc = 0; cc < NCLS; ++cc) {
        float ss = __expf(lg[0][cc] - M[cc]) + __expf(lg[1][cc] - M[cc]);
        #pragma unroll
        for (int off = 32; off; off >>= 1) ss += __shfl_xor(ss, off);
        if (lane == 0) redS[wv][cc] = ss;
    }
    __syncthreads();
    #pragma unroll
    for (int cc = 0; cc < NCLS; ++cc)
        S[cc] = (redS[0][cc] + redS[1][cc]) + (redS[2][cc] + redS[3][cc]);

    #pragma unroll
    for (int r = 0; r < 2; ++r) {
        float* o = out + ((size_t)(t0 + r) * BB + b) * NCLS;
        #pragma unroll
        for (int cc = 0; cc < NCLS; ++cc)
            o[cc] = __expf(lg[r][cc] - M[cc]) * fast_rcp(S[cc]);
    }
}

// ---------------- round-2 verified fused kernel (fallback paths) ----------------
template <bool TAB>
__global__ __launch_bounds__(64) void lstm_all(
    const int* __restrict__ x, const float* __restrict__ emb,
    const float* __restrict__ W_ih, const float* __restrict__ W_hh,
    const float* __restrict__ b_ih, const float* __restrict__ b_hh,
    const float* __restrict__ W1, const float* __restrict__ b1,
    const float* __restrict__ W2, const float* __restrict__ b2,
    const float2* __restrict__ tab, float* __restrict__ out)
{
    const int b  = blockIdx.x;
    const int j  = threadIdx.x;
    const int m  = j & 31;
    const bool lo = j < 32;
    const int rA = j, rB = j + 64;

    float whhA[HID], whhB[HID];
    #pragma unroll
    for (int k = 0; k < HID; k += 4) {
        float4 a;
        a = *(const float4*)(W_hh + rA * HID + k); whhA[k]=a.x; whhA[k+1]=a.y; whhA[k+2]=a.z; whhA[k+3]=a.w;
        a = *(const float4*)(W_hh + rB * HID + k); whhB[k]=a.x; whhB[k+1]=a.y; whhB[k+2]=a.z; whhB[k+3]=a.w;
    }
    float wihA[HID], wihB[HID];
    float biasA = 0.f, biasB = 0.f;
    if constexpr (!TAB) {
        #pragma unroll
        for (int k = 0; k < HID; k += 4) {
            float4 a;
            a = *(const float4*)(W_ih + rA * HID + k); wihA[k]=a.x; wihA[k+1]=a.y; wihA[k+2]=a.z; wihA[k+3]=a.w;
            a = *(const float4*)(W_ih + rB * HID + k); wihB[k]=a.x; wihB[k+1]=a.y; wihB[k+2]=a.z; wihB[k+3]=a.w;
        }
        biasA = b_ih[rA] + b_hh[rA];
        biasB = b_ih[rB] + b_hh[rB];
    }
    const int f16 = j & 15;
    float w1r[HID];
    #pragma unroll
    for (int k = 0; k < HID; ++k) w1r[k] = W1[f16 * HID + k];
    const int cls = j & 7;
    const int c7  = (cls < NCLS) ? cls : 0;
    float w2r[FFD];
    #pragma unroll
    for (int f = 0; f < FFD; ++f) w2r[f] = W2[c7 * FFD + f];
    const float b1v = b1[f16];
    const float b2v = b2[c7];

    float h = 0.f, c = 0.f;
    float mrun = -3.0e38f, srun = 0.f;

    auto gates = [&](float accA, float accB) {
        const float actA = sigf(accA);
        const float sB   = lo ? 2.0f * accB : accB;
        const float sgB  = sigf(sB);
        const float actB = lo ? 2.0f * sgB - 1.0f : sgB;
        const float oA = __shfl_xor(actA, 32);
        const float oB = __shfl_xor(actB, 32);
        const float gi = lo ? actA : oA;
        const float gf = lo ? oA   : actA;
        const float gg = lo ? actB : oB;
        const float go = lo ? oB   : actB;
        c = fmaf(gf, c, gi * gg);
        h = go * tanh_fast(c);
    };

    auto ff_head = [&](int t_out, const float* hsv) {
        float z0 = b1v, z1 = 0.f;
        #pragma unroll
        for (int k = 0; k < HID; k += 2) {
            z0 = fmaf(w1r[k],     hsv[k],     z0);
            z1 = fmaf(w1r[k + 1], hsv[k + 1], z1);
        }
        const float z = fmaxf(z0 + z1, 0.0f);
        float lgv = b2v;
        #pragma unroll
        for (int f = 0; f < FFD; ++f) lgv = fmaf(w2r[f], rl(z, f), lgv);
        const float mn = fmaxf(mrun, lgv);
        srun = fmaf(srun, __expf(mrun - mn), __expf(lgv - mn));
        mrun = mn;
        if (j < NCLS) out[(t_out * BB + b) * NCLS + j] = lgv;
    };

    int xvn1 = x[1 * BB + b];
    int xvn2 = x[2 * BB + b];
    float2 xg = make_float2(0.f, 0.f);
    float eA = 0.f;
    if constexpr (TAB) xg = tab[(size_t)x[b] * 64 + j];
    else               eA = emb[x[b] * EMB + m];

    if constexpr (TAB) {
        gates(xg.x, xg.y);
    } else {
        float es[EMB];
        #pragma unroll
        for (int k = 0; k < EMB; ++k) es[k] = rl(eA, k);
        float p0 = biasA, p1 = 0.f, q0 = biasB, q1 = 0.f;
        #pragma unroll
        for (int k = 0; k < EMB; k += 2) {
            p0 = fmaf(wihA[k],   es[k],   p0); p1 = fmaf(wihA[k+1], es[k+1], p1);
            q0 = fmaf(wihB[k],   es[k],   q0); q1 = fmaf(wihB[k+1], es[k+1], q1);
        }
        gates(p0 + p1, q0 + q1);
    }
    if constexpr (TAB) xg = tab[(size_t)xvn1 * 64 + j];
    else               eA = emb[xvn1 * EMB + m];
    xvn1 = xvn2;
    xvn2 = x[3 * BB + b];

    for (int t = 1; t < TT; ++t) {
        float2 xg_n = make_float2(0.f, 0.f);
        float  e_n  = 0.f;
        if (t + 1 < TT) {
            if constexpr (TAB) xg_n = tab[(size_t)xvn1 * 64 + j];
            else               e_n  = emb[xvn1 * EMB + m];
        }
        const int xv_n3 = (t + 3 < TT) ? x[(t + 3) * BB + b] : 0;

        float hsv[HID];
        #pragma unroll
        for (int k = 0; k < HID; ++k) hsv[k] = rl(h, k);

        ff_head(t - 1, hsv);

        float p0, p1 = 0.f, q0, q1 = 0.f;
        if constexpr (TAB) { p0 = xg.x; q0 = xg.y; }
        else               { p0 = biasA; q0 = biasB; }
        if constexpr (!TAB) {
            float es[EMB];
            #pragma unroll
            for (int k = 0; k < EMB; ++k) es[k] = rl(eA, k);
            #pragma unroll
            for (int k = 0; k < EMB; k += 2) {
                p0 = fmaf(wihA[k],   es[k],   p0); p1 = fmaf(wihA[k+1], es[k+1], p1);
                q0 = fmaf(wihB[k],   es[k],   q0); q1 = fmaf(wihB[k+1], es[k+1], q1);
            }
        }
        #pragma unroll
        for (int k = 0; k < HID; k += 2) {
            p0 = fmaf(whhA[k],   hsv[k],   p0); p1 = fmaf(whhA[k+1], hsv[k+1], p1);
            q0 = fmaf(whhB[k],   hsv[k],   q0); q1 = fmaf(whhB[k+1], hsv[k+1], q1);
        }
        gates(p0 + p1, q0 + q1);

        xg = xg_n; eA = e_n; xvn1 = xvn2; xvn2 = xv_n3;
    }

    {
        float hsv[HID];
        #pragma unroll
        for (int k = 0; k < HID; ++k) hsv[k] = rl(h, k);
        ff_head(TT - 1, hsv);
    }

    #pragma unroll 1
    for (int cc = 0; cc < NCLS; ++cc) {
        const float mc = rl(mrun, cc);
        const float sc = rl(srun, cc);
        const float ic = 1.0f / sc;
        #pragma unroll
        for (int i = 0; i < TT / 64; ++i) {
            const int t = j + 64 * i;
            const int a = (t * BB + b) * NCLS + cc;
            out[a] = __expf(out[a] - mc) * ic;
        }
    }
}

extern "C" void kernel_launch(void* const* d_in, const int* in_sizes, int n_in,
                              void* d_out, int out_size, void* d_ws, size_t ws_size,
                              hipStream_t stream) {
    const int*   x   = (const int*)  d_in[0];
    const float* emb = (const float*)d_in[1];
    const float* Wih = (const float*)d_in[2];
    const float* Whh = (const float*)d_in[3];
    const float* bih = (const float*)d_in[4];
    const float* bhh = (const float*)d_in[5];
    const float* W1  = (const float*)d_in[6];
    const float* b1  = (const float*)d_in[7];
    const float* W2  = (const float*)d_in[8];
    const float* b2  = (const float*)d_in[9];
    float* out = (float*)d_out;

    const size_t tab_bytes = (size_t)VOCABN * 128 * sizeof(float);   // 512 000
    const size_t hs_off    = 524288;                                 // 512 KiB align
    const size_t hs_bytes  = (size_t)BB * TT * HID * sizeof(float);  // 32 MiB
    if (ws_size >= hs_off + hs_bytes) {
        float2* tab = (float2*)d_ws;
        float*  hs  = (float*)((char*)d_ws + hs_off);
        build_xg<<<VOCABN, 64, 0, stream>>>(emb, Wih, bih, bhh, tab);
        lstm_rec<<<BB, 64, 0, stream>>>(x, tab, Whh, hs);
        ff_softmax<<<BB, 256, 0, stream>>>(hs, W1, b1, W2, b2, out);
    } else if (ws_size >= tab_bytes) {
        float2* tab = (float2*)d_ws;
        build_xg<<<VOCABN, 64, 0, stream>>>(emb, Wih, bih, bhh, tab);
        lstm_all<true><<<BB, 64, 0, stream>>>(x, emb, Wih, Whh, bih, bhh,
                                              W1, b1, W2, b2, tab, out);
    } else {
        lstm_all<false><<<BB, 64, 0, stream>>>(x, emb, Wih, Whh, bih, bhh,
                                               W1, b1, W2, b2, nullptr, out);
    }
}

// Round 6
// 289.536 us; speedup vs baseline: 2.2245x; 1.0134x over previous
//
#include <hip/hip_runtime.h>
#include <math.h>

#define TT    512
#define BB    512
#define HID   32
#define EMB   32
#define FFD   16
#define NCLS  7
#define VOCABN 1000

__device__ __forceinline__ float rl(float v, int k) {
    return __int_as_float(__builtin_amdgcn_readlane(__float_as_int(v), k));
}
__device__ __forceinline__ float fast_rcp(float x) {
#if defined(__has_builtin)
#if __has_builtin(__builtin_amdgcn_rcpf)
    return __builtin_amdgcn_rcpf(x);
#else
    return 1.0f / x;
#endif
#else
    return 1.0f / x;
#endif
}
__device__ __forceinline__ float sigf(float x) { return fast_rcp(1.0f + __expf(-x)); }
__device__ __forceinline__ float tanh_fast(float x) { return 2.0f * sigf(2.0f * x) - 1.0f; }

// xg_table[v][j] = {W_ih[j,:]·emb[v,:]+b[j], W_ih[j+64,:]·emb[v,:]+b[j+64]}
__global__ __launch_bounds__(64) void build_xg(
    const float* __restrict__ emb, const float* __restrict__ W_ih,
    const float* __restrict__ b_ih, const float* __restrict__ b_hh,
    float2* __restrict__ tab)
{
    const int v = blockIdx.x;
    const int j = threadIdx.x;
    const float* e  = emb + v * EMB;
    const float* w0 = W_ih + j * EMB;
    const float* w1 = W_ih + (j + 64) * EMB;
    float a0 = b_ih[j]      + b_hh[j];
    float a1 = b_ih[j + 64] + b_hh[j + 64];
    #pragma unroll
    for (int k = 0; k < EMB; ++k) {
        const float ek = e[k];
        a0 = fmaf(w0[k], ek, a0);
        a1 = fmaf(w1[k], ek, a1);
    }
    tab[v * 64 + j] = make_float2(a0, a1);
}

// Serial recurrence ONLY. One wave per chain.
// Round-4 evidence: FETCH_SIZE carried an extra ~8 MB = 512 waves x 16 KB =
// exactly the W_hh register-array footprint -> compiler was reloading the
// weights from memory inside the serial loop. Round-5: "+v" on float4 is
// rejected (tied indirect register input), so pin each SCALAR element (SROA
// scalarizes the const-indexed arrays) -> the asm becomes the defining op and
// in-loop reload is illegal. __launch_bounds__(64,1): full VGPR budget.
__global__ __launch_bounds__(64, 1) void lstm_rec(
    const int* __restrict__ x, const float2* __restrict__ tab,
    const float* __restrict__ W_hh, float* __restrict__ hsout)
{
    const int b  = blockIdx.x;
    const int j  = threadIdx.x;
    const int m  = j & 31;
    const bool lo = j < 32;

    __shared__ float sh[8 * HID];

    // ---- W_hh rows j and j+64 -> registers, pinned per-scalar ----
    float whhA[HID], whhB[HID];
    #pragma unroll
    for (int k = 0; k < HID; k += 4) {
        float4 a;
        a = *(const float4*)(W_hh + j * HID + k);        whhA[k]=a.x; whhA[k+1]=a.y; whhA[k+2]=a.z; whhA[k+3]=a.w;
        a = *(const float4*)(W_hh + (j + 64) * HID + k); whhB[k]=a.x; whhB[k+1]=a.y; whhB[k+2]=a.z; whhB[k+3]=a.w;
    }
    #define PIN16(A, base) \
        asm volatile("" : "+v"((A)[(base)+0]), "+v"((A)[(base)+1]), "+v"((A)[(base)+2]), "+v"((A)[(base)+3]), \
                          "+v"((A)[(base)+4]), "+v"((A)[(base)+5]), "+v"((A)[(base)+6]), "+v"((A)[(base)+7]), \
                          "+v"((A)[(base)+8]), "+v"((A)[(base)+9]), "+v"((A)[(base)+10]), "+v"((A)[(base)+11]), \
                          "+v"((A)[(base)+12]), "+v"((A)[(base)+13]), "+v"((A)[(base)+14]), "+v"((A)[(base)+15]))
    PIN16(whhA, 0); PIN16(whhA, 16);
    PIN16(whhB, 0); PIN16(whhB, 16);
    #undef PIN16

    float h = 0.f, c = 0.f;
    float* hrow0 = hsout + (size_t)b * TT * HID;

    // ---- pipeline: tab 2 deep, x 4 deep (x addrs wave-uniform -> s_load) ----
    int xc = x[2 * BB + b], xd = x[3 * BB + b];
    float2 xg  = tab[(size_t)x[b] * 64 + j];            // t=0
    float2 xg1 = tab[(size_t)x[1 * BB + b] * 64 + j];   // t=1

    for (int t8 = 0; t8 < TT / 8; ++t8) {
        #pragma unroll
        for (int u = 0; u < 8; ++u) {
            const int t = t8 * 8 + u;
            float2 xg2 = tab[(size_t)xc * 64 + j];
            const int tn = (t + 4 < TT) ? (t + 4) : (TT - 1);
            const int xnew = x[tn * BB + b];

            // broadcast h -> 32 uniform values (SGPRs)
            float hs[HID];
            #pragma unroll
            for (int k = 0; k < HID; ++k) hs[k] = rl(h, k);

            // dot: 4 chains of 16
            float p0 = xg.x, p1 = 0.f, q0 = xg.y, q1 = 0.f;
            #pragma unroll
            for (int k = 0; k < HID; k += 2) {
                p0 = fmaf(whhA[k],   hs[k],   p0); p1 = fmaf(whhA[k+1], hs[k+1], p1);
                q0 = fmaf(whhB[k],   hs[k],   q0); q1 = fmaf(whhB[k+1], hs[k+1], q1);
            }
            const float accA = p0 + p1, accB = q0 + q1;

            // lanes<32: accA->i (sig), accB->g (tanh); lanes>=32: accA->f, accB->o
            const float actA = sigf(accA);
            const float sB   = lo ? 2.0f * accB : accB;
            const float sgB  = sigf(sB);
            const float actB = lo ? 2.0f * sgB - 1.0f : sgB;
            const float oA = __shfl_xor(actA, 32);
            const float oB = __shfl_xor(actB, 32);
            const float gi = lo ? actA : oA;
            const float gf = lo ? oA   : actA;
            const float gg = lo ? actB : oB;
            const float go = lo ? oB   : actB;
            c = fmaf(gf, c, gi * gg);
            h = go * tanh_fast(c);

            if (lo) sh[u * HID + m] = h;     // LDS stage (no vmcnt)
            xg = xg1; xg1 = xg2; xc = xd; xd = xnew;
        }
        // flush 8 steps: 256 floats, one float4 per lane, coalesced 1KB store
        const float4 v = *(const float4*)(sh + j * 4);
        *(float4*)(hrow0 + t8 * 8 * HID + j * 4) = v;
    }
}

// FF + logits + softmax-over-t, one block per b, 2 timesteps per thread.
__global__ __launch_bounds__(256) void ff_softmax(
    const float* __restrict__ hs,
    const float* __restrict__ W1, const float* __restrict__ b1,
    const float* __restrict__ W2, const float* __restrict__ b2,
    float* __restrict__ out)
{
    const int b    = blockIdx.x;
    const int tid  = threadIdx.x;
    const int lane = tid & 63, wv = tid >> 6;
    const int t0   = tid * 2;

    __shared__ float redM[4][NCLS];
    __shared__ float redS[4][NCLS];

    float4 hv[16];
    const float4* hb = (const float4*)(hs + ((size_t)b * TT + t0) * HID);
    #pragma unroll
    for (int q = 0; q < 16; ++q) hv[q] = hb[q];

    float lg[2][NCLS];
    #pragma unroll
    for (int r = 0; r < 2; ++r) {
        const float* hr = (const float*)(hv + 8 * r);
        float z[FFD];
        #pragma unroll
        for (int f = 0; f < FFD; ++f) {
            float a = b1[f];
            #pragma unroll
            for (int k = 0; k < HID; ++k) a = fmaf(W1[f * HID + k], hr[k], a);
            z[f] = fmaxf(a, 0.f);
        }
        #pragma unroll
        for (int cc = 0; cc < NCLS; ++cc) {
            float a = b2[cc];
            #pragma unroll
            for (int f = 0; f < FFD; ++f) a = fmaf(W2[cc * FFD + f], z[f], a);
            lg[r][cc] = a;
        }
    }

    float M[NCLS], S[NCLS];
    #pragma unroll
    for (int cc = 0; cc < NCLS; ++cc) {
        float mm = fmaxf(lg[0][cc], lg[1][cc]);
        #pragma unroll
        for (int off = 32; off; off >>= 1) mm = fmaxf(mm, __shfl_xor(mm, off));
        if (lane == 0) redM[wv][cc] = mm;
    }
    __syncthreads();
    #pragma unroll
    for (int cc = 0; cc < NCLS; ++cc)
        M[cc] = fmaxf(fmaxf(redM[0][cc], redM[1][cc]), fmaxf(redM[2][cc], redM[3][cc]));

    #pragma unroll
    for (int cc = 0; cc < NCLS; ++cc) {
        float ss = __expf(lg[0][cc] - M[cc]) + __expf(lg[1][cc] - M[cc]);
        #pragma unroll
        for (int off = 32; off; off >>= 1) ss += __shfl_xor(ss, off);
        if (lane == 0) redS[wv][cc] = ss;
    }
    __syncthreads();
    #pragma unroll
    for (int cc = 0; cc < NCLS; ++cc)
        S[cc] = (redS[0][cc] + redS[1][cc]) + (redS[2][cc] + redS[3][cc]);

    #pragma unroll
    for (int r = 0; r < 2; ++r) {
        float* o = out + ((size_t)(t0 + r) * BB + b) * NCLS;
        #pragma unroll
        for (int cc = 0; cc < NCLS; ++cc)
            o[cc] = __expf(lg[r][cc] - M[cc]) * fast_rcp(S[cc]);
    }
}

// ---------------- round-2 verified fused kernel (fallback paths) ----------------
template <bool TAB>
__global__ __launch_bounds__(64) void lstm_all(
    const int* __restrict__ x, const float* __restrict__ emb,
    const float* __restrict__ W_ih, const float* __restrict__ W_hh,
    const float* __restrict__ b_ih, const float* __restrict__ b_hh,
    const float* __restrict__ W1, const float* __restrict__ b1,
    const float* __restrict__ W2, const float* __restrict__ b2,
    const float2* __restrict__ tab, float* __restrict__ out)
{
    const int b  = blockIdx.x;
    const int j  = threadIdx.x;
    const int m  = j & 31;
    const bool lo = j < 32;
    const int rA = j, rB = j + 64;

    float whhA[HID], whhB[HID];
    #pragma unroll
    for (int k = 0; k < HID; k += 4) {
        float4 a;
        a = *(const float4*)(W_hh + rA * HID + k); whhA[k]=a.x; whhA[k+1]=a.y; whhA[k+2]=a.z; whhA[k+3]=a.w;
        a = *(const float4*)(W_hh + rB * HID + k); whhB[k]=a.x; whhB[k+1]=a.y; whhB[k+2]=a.z; whhB[k+3]=a.w;
    }
    float wihA[HID], wihB[HID];
    float biasA = 0.f, biasB = 0.f;
    if constexpr (!TAB) {
        #pragma unroll
        for (int k = 0; k < HID; k += 4) {
            float4 a;
            a = *(const float4*)(W_ih + rA * HID + k); wihA[k]=a.x; wihA[k+1]=a.y; wihA[k+2]=a.z; wihA[k+3]=a.w;
            a = *(const float4*)(W_ih + rB * HID + k); wihB[k]=a.x; wihB[k+1]=a.y; wihB[k+2]=a.z; wihB[k+3]=a.w;
        }
        biasA = b_ih[rA] + b_hh[rA];
        biasB = b_ih[rB] + b_hh[rB];
    }
    const int f16 = j & 15;
    float w1r[HID];
    #pragma unroll
    for (int k = 0; k < HID; ++k) w1r[k] = W1[f16 * HID + k];
    const int cls = j & 7;
    const int c7  = (cls < NCLS) ? cls : 0;
    float w2r[FFD];
    #pragma unroll
    for (int f = 0; f < FFD; ++f) w2r[f] = W2[c7 * FFD + f];
    const float b1v = b1[f16];
    const float b2v = b2[c7];

    float h = 0.f, c = 0.f;
    float mrun = -3.0e38f, srun = 0.f;

    auto gates = [&](float accA, float accB) {
        const float actA = sigf(accA);
        const float sB   = lo ? 2.0f * accB : accB;
        const float sgB  = sigf(sB);
        const float actB = lo ? 2.0f * sgB - 1.0f : sgB;
        const float oA = __shfl_xor(actA, 32);
        const float oB = __shfl_xor(actB, 32);
        const float gi = lo ? actA : oA;
        const float gf = lo ? oA   : actA;
        const float gg = lo ? actB : oB;
        const float go = lo ? oB   : actB;
        c = fmaf(gf, c, gi * gg);
        h = go * tanh_fast(c);
    };

    auto ff_head = [&](int t_out, const float* hsv) {
        float z0 = b1v, z1 = 0.f;
        #pragma unroll
        for (int k = 0; k < HID; k += 2) {
            z0 = fmaf(w1r[k],     hsv[k],     z0);
            z1 = fmaf(w1r[k + 1], hsv[k + 1], z1);
        }
        const float z = fmaxf(z0 + z1, 0.0f);
        float lgv = b2v;
        #pragma unroll
        for (int f = 0; f < FFD; ++f) lgv = fmaf(w2r[f], rl(z, f), lgv);
        const float mn = fmaxf(mrun, lgv);
        srun = fmaf(srun, __expf(mrun - mn), __expf(lgv - mn));
        mrun = mn;
        if (j < NCLS) out[(t_out * BB + b) * NCLS + j] = lgv;
    };

    int xvn1 = x[1 * BB + b];
    int xvn2 = x[2 * BB + b];
    float2 xg = make_float2(0.f, 0.f);
    float eA = 0.f;
    if constexpr (TAB) xg = tab[(size_t)x[b] * 64 + j];
    else               eA = emb[x[b] * EMB + m];

    if constexpr (TAB) {
        gates(xg.x, xg.y);
    } else {
        float es[EMB];
        #pragma unroll
        for (int k = 0; k < EMB; ++k) es[k] = rl(eA, k);
        float p0 = biasA, p1 = 0.f, q0 = biasB, q1 = 0.f;
        #pragma unroll
        for (int k = 0; k < EMB; k += 2) {
            p0 = fmaf(wihA[k],   es[k],   p0); p1 = fmaf(wihA[k+1], es[k+1], p1);
            q0 = fmaf(wihB[k],   es[k],   q0); q1 = fmaf(wihB[k+1], es[k+1], q1);
        }
        gates(p0 + p1, q0 + q1);
    }
    if constexpr (TAB) xg = tab[(size_t)xvn1 * 64 + j];
    else               eA = emb[xvn1 * EMB + m];
    xvn1 = xvn2;
    xvn2 = x[3 * BB + b];

    for (int t = 1; t < TT; ++t) {
        float2 xg_n = make_float2(0.f, 0.f);
        float  e_n  = 0.f;
        if (t + 1 < TT) {
            if constexpr (TAB) xg_n = tab[(size_t)xvn1 * 64 + j];
            else               e_n  = emb[xvn1 * EMB + m];
        }
        const int xv_n3 = (t + 3 < TT) ? x[(t + 3) * BB + b] : 0;

        float hsv[HID];
        #pragma unroll
        for (int k = 0; k < HID; ++k) hsv[k] = rl(h, k);

        ff_head(t - 1, hsv);

        float p0, p1 = 0.f, q0, q1 = 0.f;
        if constexpr (TAB) { p0 = xg.x; q0 = xg.y; }
        else               { p0 = biasA; q0 = biasB; }
        if constexpr (!TAB) {
            float es[EMB];
            #pragma unroll
            for (int k = 0; k < EMB; ++k) es[k] = rl(eA, k);
            #pragma unroll
            for (int k = 0; k < EMB; k += 2) {
                p0 = fmaf(wihA[k],   es[k],   p0); p1 = fmaf(wihA[k+1], es[k+1], p1);
                q0 = fmaf(wihB[k],   es[k],   q0); q1 = fmaf(wihB[k+1], es[k+1], q1);
            }
        }
        #pragma unroll
        for (int k = 0; k < HID; k += 2) {
            p0 = fmaf(whhA[k],   hsv[k],   p0); p1 = fmaf(whhA[k+1], hsv[k+1], p1);
            q0 = fmaf(whhB[k],   hsv[k],   q0); q1 = fmaf(whhB[k+1], hsv[k+1], q1);
        }
        gates(p0 + p1, q0 + q1);

        xg = xg_n; eA = e_n; xvn1 = xvn2; xvn2 = xv_n3;
    }

    {
        float hsv[HID];
        #pragma unroll
        for (int k = 0; k < HID; ++k) hsv[k] = rl(h, k);
        ff_head(TT - 1, hsv);
    }

    #pragma unroll 1
    for (int cc = 0; cc < NCLS; ++cc) {
        const float mc = rl(mrun, cc);
        const float sc = rl(srun, cc);
        const float ic = 1.0f / sc;
        #pragma unroll
        for (int i = 0; i < TT / 64; ++i) {
            const int t = j + 64 * i;
            const int a = (t * BB + b) * NCLS + cc;
            out[a] = __expf(out[a] - mc) * ic;
        }
    }
}

extern "C" void kernel_launch(void* const* d_in, const int* in_sizes, int n_in,
                              void* d_out, int out_size, void* d_ws, size_t ws_size,
                              hipStream_t stream) {
    const int*   x   = (const int*)  d_in[0];
    const float* emb = (const float*)d_in[1];
    const float* Wih = (const float*)d_in[2];
    const float* Whh = (const float*)d_in[3];
    const float* bih = (const float*)d_in[4];
    const float* bhh = (const float*)d_in[5];
    const float* W1  = (const float*)d_in[6];
    const float* b1  = (const float*)d_in[7];
    const float* W2  = (const float*)d_in[8];
    const float* b2  = (const float*)d_in[9];
    float* out = (float*)d_out;

    const size_t tab_bytes = (size_t)VOCABN * 128 * sizeof(float);   // 512 000
    const size_t hs_off    = 524288;                                 // 512 KiB align
    const size_t hs_bytes  = (size_t)BB * TT * HID * sizeof(float);  // 32 MiB
    if (ws_size >= hs_off + hs_bytes) {
        float2* tab = (float2*)d_ws;
        float*  hs  = (float*)((char*)d_ws + hs_off);
        build_xg<<<VOCABN, 64, 0, stream>>>(emb, Wih, bih, bhh, tab);
        lstm_rec<<<BB, 64, 0, stream>>>(x, tab, Whh, hs);
        ff_softmax<<<BB, 256, 0, stream>>>(hs, W1, b1, W2, b2, out);
    } else if (ws_size >= tab_bytes) {
        float2* tab = (float2*)d_ws;
        build_xg<<<VOCABN, 64, 0, stream>>>(emb, Wih, bih, bhh, tab);
        lstm_all<true><<<BB, 64, 0, stream>>>(x, emb, Wih, Whh, bih, bhh,
                                              W1, b1, W2, b2, tab, out);
    } else {
        lstm_all<false><<<BB, 64, 0, stream>>>(x, emb, Wih, Whh, bih, bhh,
                                               W1, b1, W2, b2, nullptr, out);
    }
}